// Round 1
// baseline (265.977 us; speedup 1.0000x reference)
//
#include <hip/hip_runtime.h>
#include <math.h>

// ws layout (float offsets)
#define WS_FOCAL 0
#define WS_CONS  2     // 6 floats: S0,S1,S2,P01,P02,P12
#define WS_AREA  8     // 32
#define WS_EX    40    // 32
#define WS_EY    72    // 32
#define WS_POS   104   // 1024
#define WS_INORM 1152  // 1024
#define WS_PART  2176  // 1024*16*2 (m,s) pairs
#define ZERO_FLOATS 104

__device__ inline float wave_reduce(float v) {
#pragma unroll
  for (int m = 32; m >= 1; m >>= 1) v += __shfl_xor(v, m);
  return v;
}

__device__ inline float focal_px(float v0, float v1, float v2, float v3,
                                 float v4, float v5, float v6, float v7, int tt) {
  float mx = fmaxf(fmaxf(fmaxf(v0, v1), fmaxf(v2, v3)),
                   fmaxf(fmaxf(v4, v5), fmaxf(v6, v7)));
  float se = expf(v0 - mx) + expf(v1 - mx) + expf(v2 - mx) + expf(v3 - mx) +
             expf(v4 - mx) + expf(v5 - mx) + expf(v6 - mx) + expf(v7 - mx);
  float xt = v0;
  xt = (tt == 1) ? v1 : xt;
  xt = (tt == 2) ? v2 : xt;
  xt = (tt == 3) ? v3 : xt;
  xt = (tt == 4) ? v4 : xt;
  xt = (tt == 5) ? v5 : xt;
  xt = (tt == 6) ? v6 : xt;
  xt = (tt == 7) ? v7 : xt;
  float lp = (xt - mx) - logf(se);
  float p = expf(lp);
  float om = 1.0f - p;
  return 0.25f * om * om * (-lp);
}

// blocks [0,2048): focal     (524288 float4-pixel-groups)
// blocks [2048,2560): circularity (32 images x 16 parts)
// blocks [2560,4608): consensus
// blocks [4608,4864): feature row norms (1024 rows, 1 wave each)
__global__ __launch_bounds__(256) void mega_kernel(
    const float* __restrict__ logits, const int* __restrict__ target,
    const float* __restrict__ feat, const float* __restrict__ masks,
    const float* __restrict__ preds, float* __restrict__ ws) {
  __shared__ float red[32];
  const int bid = blockIdx.x;
  const int tid = threadIdx.x;
  const int lane = tid & 63;
  const int wid = tid >> 6;

  if (bid < 2048) {
    // ---------------- focal ----------------
    int t = bid * 256 + tid;          // 0..524287
    int p4 = t * 4;                   // pixel base
    int b = p4 >> 16;
    int hw = p4 & 65535;
    const float* lb = logits + (b << 19) + hw;  // b*8*65536
    float4 x0 = *(const float4*)(lb + (0 << 16));
    float4 x1 = *(const float4*)(lb + (1 << 16));
    float4 x2 = *(const float4*)(lb + (2 << 16));
    float4 x3 = *(const float4*)(lb + (3 << 16));
    float4 x4 = *(const float4*)(lb + (4 << 16));
    float4 x5 = *(const float4*)(lb + (5 << 16));
    float4 x6 = *(const float4*)(lb + (6 << 16));
    float4 x7 = *(const float4*)(lb + (7 << 16));
    int4 tg = *(const int4*)(target + p4);
    float acc = 0.0f;
    acc += focal_px(x0.x, x1.x, x2.x, x3.x, x4.x, x5.x, x6.x, x7.x, tg.x);
    acc += focal_px(x0.y, x1.y, x2.y, x3.y, x4.y, x5.y, x6.y, x7.y, tg.y);
    acc += focal_px(x0.z, x1.z, x2.z, x3.z, x4.z, x5.z, x6.z, x7.z, tg.z);
    acc += focal_px(x0.w, x1.w, x2.w, x3.w, x4.w, x5.w, x6.w, x7.w, tg.w);
    float v = wave_reduce(acc);
    if (lane == 0) red[wid] = v;
    __syncthreads();
    if (tid == 0) atomicAdd(ws + WS_FOCAL, red[0] + red[1] + red[2] + red[3]);

  } else if (bid < 2560) {
    // ---------------- circularity (masks channel 0 only) ----------------
    int bi = bid - 2048;
    int img = bi >> 4;
    int part = bi & 15;
    const float* mS = masks + img * 3 * 65536;  // channel 0 of image img
    const float4* m4 = (const float4*)mS;
    float a = 0.0f, ex = 0.0f, ey = 0.0f;
#pragma unroll
    for (int i = 0; i < 4; i++) {
      int v = tid + 256 * i;          // 0..1023
      int rl = v >> 6;                // 0..15
      int c4 = v & 63;                // float4 col
      int row = part * 16 + rl;
      float4 val = m4[row * 64 + c4];
      a += val.x + val.y + val.z + val.w;
      ey += fabsf(val.y - val.x) + fabsf(val.z - val.y) + fabsf(val.w - val.z);
      if (c4 > 0) ey += fabsf(val.x - mS[row * 256 + c4 * 4 - 1]);
      if (row > 0) {
        float4 u = m4[(row - 1) * 64 + c4];
        ex += fabsf(val.x - u.x) + fabsf(val.y - u.y) +
              fabsf(val.z - u.z) + fabsf(val.w - u.w);
      }
    }
    float ra = wave_reduce(a);
    float rx = wave_reduce(ex);
    float ry = wave_reduce(ey);
    if (lane == 0) {
      red[wid + 0] = ra;
      red[wid + 4] = rx;
      red[wid + 8] = ry;
    }
    __syncthreads();
    if (tid == 0) {
      atomicAdd(ws + WS_AREA + img, red[0] + red[1] + red[2] + red[3]);
      atomicAdd(ws + WS_EX + img, red[4] + red[5] + red[6] + red[7]);
      atomicAdd(ws + WS_EY + img, red[8] + red[9] + red[10] + red[11]);
    }

  } else if (bid < 4608) {
    // ---------------- consensus ----------------
    int t = (bid - 2560) * 256 + tid;  // 0..524287 float4s per plane
    const float4* q = (const float4*)preds;
    float4 a0 = q[t];
    float4 a1 = q[t + 524288];
    float4 a2 = q[t + 1048576];
    float s0 = a0.x + a0.y + a0.z + a0.w;
    float s1 = a1.x + a1.y + a1.z + a1.w;
    float s2 = a2.x + a2.y + a2.z + a2.w;
    float p01 = a0.x * a1.x + a0.y * a1.y + a0.z * a1.z + a0.w * a1.w;
    float p02 = a0.x * a2.x + a0.y * a2.y + a0.z * a2.z + a0.w * a2.w;
    float p12 = a1.x * a2.x + a1.y * a2.y + a1.z * a2.z + a1.w * a2.w;
    float r0 = wave_reduce(s0);
    float r1 = wave_reduce(s1);
    float r2 = wave_reduce(s2);
    float r3 = wave_reduce(p01);
    float r4 = wave_reduce(p02);
    float r5 = wave_reduce(p12);
    if (lane == 0) {
      red[wid + 0] = r0; red[wid + 4] = r1; red[wid + 8] = r2;
      red[wid + 12] = r3; red[wid + 16] = r4; red[wid + 20] = r5;
    }
    __syncthreads();
    if (tid == 0) {
#pragma unroll
      for (int k = 0; k < 6; k++)
        atomicAdd(ws + WS_CONS + k,
                  red[k * 4] + red[k * 4 + 1] + red[k * 4 + 2] + red[k * 4 + 3]);
    }

  } else {
    // ---------------- feature row norms ----------------
    int row = (bid - 4608) * 4 + wid;  // 0..1023
    const float4* f4 = (const float4*)feat;
    float4 u = f4[row * 128 + lane];
    float4 w = f4[row * 128 + 64 + lane];
    float s = u.x * u.x + u.y * u.y + u.z * u.z + u.w * u.w +
              w.x * w.x + w.y * w.y + w.z * w.z + w.w * w.w;
    s = wave_reduce(s);
    if (lane == 0) ws[WS_INORM + row] = 1.0f / sqrtf(s);
  }
}

// sim tiles 64x64 over k=512, fused partial logsumexp per (row, coltile)
__global__ __launch_bounds__(256) void sim_kernel(const float* __restrict__ feat,
                                                  float* __restrict__ ws) {
  __shared__ float A[64 * 68];
  __shared__ float B[64 * 68];
  const int tid = threadIdx.x;
  const int rt = blockIdx.x >> 4;
  const int ct = blockIdx.x & 15;
  const int rb = rt * 64, cb = ct * 64;
  const int rg = tid >> 3;  // 0..31
  const int cg = tid & 7;   // 0..7
  float acc0[8], acc1[8];
#pragma unroll
  for (int u = 0; u < 8; u++) { acc0[u] = 0.0f; acc1[u] = 0.0f; }

  for (int kb = 0; kb < 512; kb += 64) {
    __syncthreads();
#pragma unroll
    for (int i = 0; i < 4; i++) {
      int v = tid + 256 * i;     // 0..1023 float4 slots
      int row = v >> 4;
      int k4 = (v & 15) << 2;
      *(float4*)&A[row * 68 + k4] = *(const float4*)(feat + (rb + row) * 512 + kb + k4);
      *(float4*)&B[row * 68 + k4] = *(const float4*)(feat + (cb + row) * 512 + kb + k4);
    }
    __syncthreads();
#pragma unroll
    for (int k4 = 0; k4 < 64; k4 += 4) {
      float4 a0 = *(float4*)&A[rg * 68 + k4];
      float4 a1 = *(float4*)&A[(rg + 32) * 68 + k4];
#pragma unroll
      for (int u = 0; u < 8; u++) {
        float4 b = *(float4*)&B[(cg + 8 * u) * 68 + k4];
        acc0[u] = fmaf(a0.w, b.w, fmaf(a0.z, b.z, fmaf(a0.y, b.y, fmaf(a0.x, b.x, acc0[u]))));
        acc1[u] = fmaf(a1.w, b.w, fmaf(a1.z, b.z, fmaf(a1.y, b.y, fmaf(a1.x, b.x, acc1[u]))));
      }
    }
  }

  const float INVT = 1.0f / 0.07f;
  int gr0 = rb + rg, gr1 = rb + rg + 32;
  float nr0 = ws[WS_INORM + gr0] * INVT;
  float nr1 = ws[WS_INORM + gr1] * INVT;
  int pos0 = (gr0 + 512) & 1023;
  int pos1 = (gr1 + 512) & 1023;
  float v0[8], v1[8];
  float m0 = -3e38f, m1 = -3e38f;
#pragma unroll
  for (int u = 0; u < 8; u++) {
    int gc = cb + cg + 8 * u;
    float cn = ws[WS_INORM + gc];
    float a = acc0[u] * nr0 * cn;
    float c = acc1[u] * nr1 * cn;
    if (gc == pos0) ws[WS_POS + gr0] = a;
    if (gc == pos1) ws[WS_POS + gr1] = c;
    if (gc == gr0) a = -1e30f;
    if (gc == gr1) c = -1e30f;
    v0[u] = a; v1[u] = c;
    m0 = fmaxf(m0, a); m1 = fmaxf(m1, c);
  }
  float s0 = 0.0f, s1 = 0.0f;
#pragma unroll
  for (int u = 0; u < 8; u++) {
    s0 += expf(v0[u] - m0);
    s1 += expf(v1[u] - m1);
  }
#pragma unroll
  for (int d = 1; d < 8; d <<= 1) {
    float mo = __shfl_xor(m0, d), so = __shfl_xor(s0, d);
    float nm = fmaxf(m0, mo);
    s0 = s0 * expf(m0 - nm) + so * expf(mo - nm);
    m0 = nm;
    mo = __shfl_xor(m1, d); so = __shfl_xor(s1, d);
    nm = fmaxf(m1, mo);
    s1 = s1 * expf(m1 - nm) + so * expf(mo - nm);
    m1 = nm;
  }
  if (cg == 0) {
    float2* part = (float2*)(ws + WS_PART);
    part[gr0 * 16 + ct] = make_float2(m0, s0);
    part[gr1 * 16 + ct] = make_float2(m1, s1);
  }
}

__global__ __launch_bounds__(1024) void final_kernel(float* __restrict__ ws,
                                                     float* __restrict__ out) {
  __shared__ float red[16];
  int r = threadIdx.x;  // row 0..1023
  const float2* part = (const float2*)(ws + WS_PART);
  float M = -1e30f, S = 0.0f;
#pragma unroll
  for (int ctl = 0; ctl < 16; ctl++) {
    float2 p = part[r * 16 + ctl];
    float nm = fmaxf(M, p.x);
    S = S * expf(M - nm) + p.y * expf(p.x - nm);
    M = nm;
  }
  float lse = M + logf(S);
  float v = lse - ws[WS_POS + r];
  v = wave_reduce(v);
  if ((r & 63) == 0) red[r >> 6] = v;
  __syncthreads();
  if (r == 0) {
    float tot = 0.0f;
#pragma unroll
    for (int i = 0; i < 16; i++) tot += red[i];
    float contr = tot / 1024.0f;
    float focal = ws[WS_FOCAL] / 2097152.0f;
    float S0 = ws[2], S1 = ws[3], S2 = ws[4];
    float P01 = ws[5], P02 = ws[6], P12 = ws[7];
    float cons = 0.0f;
    cons += fmaxf(0.6f - P01 / (S0 + S1 - P01 + 1e-6f), 0.0f);
    cons += fmaxf(0.6f - P02 / (S0 + S2 - P02 + 1e-6f), 0.0f);
    cons += fmaxf(0.6f - P12 / (S1 + S2 - P12 + 1e-6f), 0.0f);
    cons *= (1.0f / 3.0f);
    float circ = 0.0f;
    for (int b = 0; b < 32; b++) {
      float area = ws[WS_AREA + b];
      float per = ws[WS_EX + b] + ws[WS_EY + b];
      float d = fmaxf(per, 1e-12f);
      float c = 12.566370614359172f * area / (d * d);
      float li = (area > 0.0f && per > 0.0f) ? (c - 1.0f) * (c - 1.0f) : 0.0f;
      circ += li;
    }
    circ = 0.1f * circ / 32.0f;
    out[0] = focal + 0.5f * contr + circ + 0.3f * cons;
  }
}

extern "C" void kernel_launch(void* const* d_in, const int* in_sizes, int n_in,
                              void* d_out, int out_size, void* d_ws, size_t ws_size,
                              hipStream_t stream) {
  const float* logits = (const float*)d_in[0];
  const int* target = (const int*)d_in[1];
  const float* feat = (const float*)d_in[2];
  const float* masks = (const float*)d_in[3];
  const float* preds = (const float*)d_in[4];
  float* ws = (float*)d_ws;
  float* out = (float*)d_out;

  hipMemsetAsync(d_ws, 0, ZERO_FLOATS * sizeof(float), stream);
  mega_kernel<<<4864, 256, 0, stream>>>(logits, target, feat, masks, preds, ws);
  sim_kernel<<<256, 256, 0, stream>>>(feat, ws);
  final_kernel<<<1, 1024, 0, stream>>>(ws, out);
}

// Round 2
// 87.252 us; speedup vs baseline: 3.0484x; 3.0484x over previous
//
#include <hip/hip_runtime.h>
#include <math.h>

// ws layout (float offsets) — every slot written fresh each call, no atomics
#define WS_FOCALP 0        // 2048 focal block partials
#define WS_CONSP  2048     // 6*2048 consensus partials, [k][b]
#define WS_AREAP  14336    // 512 (img*16+part)
#define WS_EXP_   14848    // 512
#define WS_EYP_   15360    // 512
#define WS_POS    15872    // 1024
#define WS_INORM  16896    // 1024
#define WS_PART   17920    // 1024*16 float2 (m,s)

__device__ inline float wave_reduce(float v) {
#pragma unroll
  for (int m = 32; m >= 1; m >>= 1) v += __shfl_xor(v, m);
  return v;
}

__device__ inline float focal_px(float v0, float v1, float v2, float v3,
                                 float v4, float v5, float v6, float v7, int tt) {
  float mx = fmaxf(fmaxf(fmaxf(v0, v1), fmaxf(v2, v3)),
                   fmaxf(fmaxf(v4, v5), fmaxf(v6, v7)));
  float se = expf(v0 - mx) + expf(v1 - mx) + expf(v2 - mx) + expf(v3 - mx) +
             expf(v4 - mx) + expf(v5 - mx) + expf(v6 - mx) + expf(v7 - mx);
  float xt = v0;
  xt = (tt == 1) ? v1 : xt;
  xt = (tt == 2) ? v2 : xt;
  xt = (tt == 3) ? v3 : xt;
  xt = (tt == 4) ? v4 : xt;
  xt = (tt == 5) ? v5 : xt;
  xt = (tt == 6) ? v6 : xt;
  xt = (tt == 7) ? v7 : xt;
  float lp = (xt - mx) - logf(se);
  float p = expf(lp);
  float om = 1.0f - p;
  return 0.25f * om * om * (-lp);
}

// blocks [0,2048): focal     (524288 float4-pixel-groups)
// blocks [2048,2560): circularity (32 images x 16 parts)
// blocks [2560,4608): consensus
// blocks [4608,4864): feature row norms (1024 rows, 1 wave each)
__global__ __launch_bounds__(256) void mega_kernel(
    const float* __restrict__ logits, const int* __restrict__ target,
    const float* __restrict__ feat, const float* __restrict__ masks,
    const float* __restrict__ preds, float* __restrict__ ws) {
  __shared__ float red[32];
  const int bid = blockIdx.x;
  const int tid = threadIdx.x;
  const int lane = tid & 63;
  const int wid = tid >> 6;

  if (bid < 2048) {
    // ---------------- focal ----------------
    int t = bid * 256 + tid;          // 0..524287
    int p4 = t * 4;                   // pixel base
    int b = p4 >> 16;
    int hw = p4 & 65535;
    const float* lb = logits + (b << 19) + hw;  // b*8*65536
    float4 x0 = *(const float4*)(lb + (0 << 16));
    float4 x1 = *(const float4*)(lb + (1 << 16));
    float4 x2 = *(const float4*)(lb + (2 << 16));
    float4 x3 = *(const float4*)(lb + (3 << 16));
    float4 x4 = *(const float4*)(lb + (4 << 16));
    float4 x5 = *(const float4*)(lb + (5 << 16));
    float4 x6 = *(const float4*)(lb + (6 << 16));
    float4 x7 = *(const float4*)(lb + (7 << 16));
    int4 tg = *(const int4*)(target + p4);
    float acc = 0.0f;
    acc += focal_px(x0.x, x1.x, x2.x, x3.x, x4.x, x5.x, x6.x, x7.x, tg.x);
    acc += focal_px(x0.y, x1.y, x2.y, x3.y, x4.y, x5.y, x6.y, x7.y, tg.y);
    acc += focal_px(x0.z, x1.z, x2.z, x3.z, x4.z, x5.z, x6.z, x7.z, tg.z);
    acc += focal_px(x0.w, x1.w, x2.w, x3.w, x4.w, x5.w, x6.w, x7.w, tg.w);
    float v = wave_reduce(acc);
    if (lane == 0) red[wid] = v;
    __syncthreads();
    if (tid == 0) ws[WS_FOCALP + bid] = red[0] + red[1] + red[2] + red[3];

  } else if (bid < 2560) {
    // ---------------- circularity (masks channel 0 only) ----------------
    int bi = bid - 2048;
    int img = bi >> 4;
    int part = bi & 15;
    const float* mS = masks + img * 3 * 65536;  // channel 0 of image img
    const float4* m4 = (const float4*)mS;
    float a = 0.0f, ex = 0.0f, ey = 0.0f;
#pragma unroll
    for (int i = 0; i < 4; i++) {
      int v = tid + 256 * i;          // 0..1023
      int rl = v >> 6;                // 0..15
      int c4 = v & 63;                // float4 col
      int row = part * 16 + rl;
      float4 val = m4[row * 64 + c4];
      a += val.x + val.y + val.z + val.w;
      ey += fabsf(val.y - val.x) + fabsf(val.z - val.y) + fabsf(val.w - val.z);
      if (c4 > 0) ey += fabsf(val.x - mS[row * 256 + c4 * 4 - 1]);
      if (row > 0) {
        float4 u = m4[(row - 1) * 64 + c4];
        ex += fabsf(val.x - u.x) + fabsf(val.y - u.y) +
              fabsf(val.z - u.z) + fabsf(val.w - u.w);
      }
    }
    float ra = wave_reduce(a);
    float rx = wave_reduce(ex);
    float ry = wave_reduce(ey);
    if (lane == 0) {
      red[wid + 0] = ra;
      red[wid + 4] = rx;
      red[wid + 8] = ry;
    }
    __syncthreads();
    if (tid == 0) {
      ws[WS_AREAP + bi] = red[0] + red[1] + red[2] + red[3];
      ws[WS_EXP_ + bi] = red[4] + red[5] + red[6] + red[7];
      ws[WS_EYP_ + bi] = red[8] + red[9] + red[10] + red[11];
    }

  } else if (bid < 4608) {
    // ---------------- consensus ----------------
    int b = bid - 2560;                // 0..2047
    int t = b * 256 + tid;             // 0..524287 float4s per plane
    const float4* q = (const float4*)preds;
    float4 a0 = q[t];
    float4 a1 = q[t + 524288];
    float4 a2 = q[t + 1048576];
    float s0 = a0.x + a0.y + a0.z + a0.w;
    float s1 = a1.x + a1.y + a1.z + a1.w;
    float s2 = a2.x + a2.y + a2.z + a2.w;
    float p01 = a0.x * a1.x + a0.y * a1.y + a0.z * a1.z + a0.w * a1.w;
    float p02 = a0.x * a2.x + a0.y * a2.y + a0.z * a2.z + a0.w * a2.w;
    float p12 = a1.x * a2.x + a1.y * a2.y + a1.z * a2.z + a1.w * a2.w;
    float r0 = wave_reduce(s0);
    float r1 = wave_reduce(s1);
    float r2 = wave_reduce(s2);
    float r3 = wave_reduce(p01);
    float r4 = wave_reduce(p02);
    float r5 = wave_reduce(p12);
    if (lane == 0) {
      red[wid + 0] = r0; red[wid + 4] = r1; red[wid + 8] = r2;
      red[wid + 12] = r3; red[wid + 16] = r4; red[wid + 20] = r5;
    }
    __syncthreads();
    if (tid == 0) {
#pragma unroll
      for (int k = 0; k < 6; k++)
        ws[WS_CONSP + k * 2048 + b] =
            red[k * 4] + red[k * 4 + 1] + red[k * 4 + 2] + red[k * 4 + 3];
    }

  } else {
    // ---------------- feature row norms ----------------
    int row = (bid - 4608) * 4 + wid;  // 0..1023
    const float4* f4 = (const float4*)feat;
    float4 u = f4[row * 128 + lane];
    float4 w = f4[row * 128 + 64 + lane];
    float s = u.x * u.x + u.y * u.y + u.z * u.z + u.w * u.w +
              w.x * w.x + w.y * w.y + w.z * w.z + w.w * w.w;
    s = wave_reduce(s);
    if (lane == 0) ws[WS_INORM + row] = 1.0f / sqrtf(s);
  }
}

// sim tiles 64x64 over k=512, fused partial logsumexp per (row, coltile)
__global__ __launch_bounds__(256) void sim_kernel(const float* __restrict__ feat,
                                                  float* __restrict__ ws) {
  __shared__ float A[64 * 68];
  __shared__ float B[64 * 68];
  const int tid = threadIdx.x;
  const int rt = blockIdx.x >> 4;
  const int ct = blockIdx.x & 15;
  const int rb = rt * 64, cb = ct * 64;
  const int rg = tid >> 3;  // 0..31
  const int cg = tid & 7;   // 0..7
  float acc0[8], acc1[8];
#pragma unroll
  for (int u = 0; u < 8; u++) { acc0[u] = 0.0f; acc1[u] = 0.0f; }

  for (int kb = 0; kb < 512; kb += 64) {
    __syncthreads();
#pragma unroll
    for (int i = 0; i < 4; i++) {
      int v = tid + 256 * i;     // 0..1023 float4 slots
      int row = v >> 4;
      int k4 = (v & 15) << 2;
      *(float4*)&A[row * 68 + k4] = *(const float4*)(feat + (rb + row) * 512 + kb + k4);
      *(float4*)&B[row * 68 + k4] = *(const float4*)(feat + (cb + row) * 512 + kb + k4);
    }
    __syncthreads();
#pragma unroll
    for (int k4 = 0; k4 < 64; k4 += 4) {
      float4 a0 = *(float4*)&A[rg * 68 + k4];
      float4 a1 = *(float4*)&A[(rg + 32) * 68 + k4];
#pragma unroll
      for (int u = 0; u < 8; u++) {
        float4 b = *(float4*)&B[(cg + 8 * u) * 68 + k4];
        acc0[u] = fmaf(a0.w, b.w, fmaf(a0.z, b.z, fmaf(a0.y, b.y, fmaf(a0.x, b.x, acc0[u]))));
        acc1[u] = fmaf(a1.w, b.w, fmaf(a1.z, b.z, fmaf(a1.y, b.y, fmaf(a1.x, b.x, acc1[u]))));
      }
    }
  }

  const float INVT = 1.0f / 0.07f;
  int gr0 = rb + rg, gr1 = rb + rg + 32;
  float nr0 = ws[WS_INORM + gr0] * INVT;
  float nr1 = ws[WS_INORM + gr1] * INVT;
  int pos0 = (gr0 + 512) & 1023;
  int pos1 = (gr1 + 512) & 1023;
  float v0[8], v1[8];
  float m0 = -3e38f, m1 = -3e38f;
#pragma unroll
  for (int u = 0; u < 8; u++) {
    int gc = cb + cg + 8 * u;
    float cn = ws[WS_INORM + gc];
    float a = acc0[u] * nr0 * cn;
    float c = acc1[u] * nr1 * cn;
    if (gc == pos0) ws[WS_POS + gr0] = a;
    if (gc == pos1) ws[WS_POS + gr1] = c;
    if (gc == gr0) a = -1e30f;
    if (gc == gr1) c = -1e30f;
    v0[u] = a; v1[u] = c;
    m0 = fmaxf(m0, a); m1 = fmaxf(m1, c);
  }
  float s0 = 0.0f, s1 = 0.0f;
#pragma unroll
  for (int u = 0; u < 8; u++) {
    s0 += expf(v0[u] - m0);
    s1 += expf(v1[u] - m1);
  }
#pragma unroll
  for (int d = 1; d < 8; d <<= 1) {
    float mo = __shfl_xor(m0, d), so = __shfl_xor(s0, d);
    float nm = fmaxf(m0, mo);
    s0 = s0 * expf(m0 - nm) + so * expf(mo - nm);
    m0 = nm;
    mo = __shfl_xor(m1, d); so = __shfl_xor(s1, d);
    nm = fmaxf(m1, mo);
    s1 = s1 * expf(m1 - nm) + so * expf(mo - nm);
    m1 = nm;
  }
  if (cg == 0) {
    float2* part = (float2*)(ws + WS_PART);
    part[gr0 * 16 + ct] = make_float2(m0, s0);
    part[gr1 * 16 + ct] = make_float2(m1, s1);
  }
}

// returns block total at tid==0 (valid only there)
__device__ inline float block_reduce_1024(float v, float* red) {
  int tid = threadIdx.x;
  v = wave_reduce(v);
  __syncthreads();  // protect red from previous use
  if ((tid & 63) == 0) red[tid >> 6] = v;
  __syncthreads();
  float t = 0.0f;
  if (tid == 0) {
#pragma unroll
    for (int i = 0; i < 16; i++) t += red[i];
  }
  return t;
}

__global__ __launch_bounds__(1024) void final_kernel(float* __restrict__ ws,
                                                     float* __restrict__ out) {
  __shared__ float red[16];
  __shared__ float li_s[32];
  int r = threadIdx.x;  // 0..1023

  // ---- contrastive LSE merge ----
  const float2* part = (const float2*)(ws + WS_PART);
  float M = -1e30f, S = 0.0f;
#pragma unroll
  for (int ctl = 0; ctl < 16; ctl++) {
    float2 p = part[r * 16 + ctl];
    float nm = fmaxf(M, p.x);
    S = S * expf(M - nm) + p.y * expf(p.x - nm);
    M = nm;
  }
  float lse = M + logf(S);
  float contr_sum = block_reduce_1024(lse - ws[WS_POS + r], red);

  // ---- focal partials ----
  float focal_sum =
      block_reduce_1024(ws[WS_FOCALP + r] + ws[WS_FOCALP + r + 1024], red);

  // ---- consensus partials (6 reductions) ----
  float cons[6];
#pragma unroll
  for (int k = 0; k < 6; k++) {
    const float* p = ws + WS_CONSP + k * 2048;
    cons[k] = block_reduce_1024(p[r] + p[r + 1024], red);
  }

  // ---- circularity: 32 imgs x 16 parts ----
  float li = 0.0f;
  if (r < 512) {
    float a = ws[WS_AREAP + r];
    float ex = ws[WS_EXP_ + r];
    float ey = ws[WS_EYP_ + r];
#pragma unroll
    for (int d = 1; d < 16; d <<= 1) {
      a += __shfl_xor(a, d);
      ex += __shfl_xor(ex, d);
      ey += __shfl_xor(ey, d);
    }
    if ((r & 15) == 0) {
      float per = ex + ey;
      float dd = fmaxf(per, 1e-12f);
      float c = 12.566370614359172f * a / (dd * dd);
      li = (a > 0.0f && per > 0.0f) ? (c - 1.0f) * (c - 1.0f) : 0.0f;
      li_s[r >> 4] = li;
    }
  }
  __syncthreads();

  if (r == 0) {
    float circ = 0.0f;
#pragma unroll
    for (int i = 0; i < 32; i++) circ += li_s[i];
    circ = 0.1f * circ / 32.0f;

    float contr = contr_sum / 1024.0f;
    float focal = focal_sum / 2097152.0f;

    float S0 = cons[0], S1 = cons[1], S2 = cons[2];
    float P01 = cons[3], P02 = cons[4], P12 = cons[5];
    float co = 0.0f;
    co += fmaxf(0.6f - P01 / (S0 + S1 - P01 + 1e-6f), 0.0f);
    co += fmaxf(0.6f - P02 / (S0 + S2 - P02 + 1e-6f), 0.0f);
    co += fmaxf(0.6f - P12 / (S1 + S2 - P12 + 1e-6f), 0.0f);
    co *= (1.0f / 3.0f);

    out[0] = focal + 0.5f * contr + circ + 0.3f * co;
  }
}

extern "C" void kernel_launch(void* const* d_in, const int* in_sizes, int n_in,
                              void* d_out, int out_size, void* d_ws, size_t ws_size,
                              hipStream_t stream) {
  const float* logits = (const float*)d_in[0];
  const int* target = (const int*)d_in[1];
  const float* feat = (const float*)d_in[2];
  const float* masks = (const float*)d_in[3];
  const float* preds = (const float*)d_in[4];
  float* ws = (float*)d_ws;
  float* out = (float*)d_out;

  mega_kernel<<<4864, 256, 0, stream>>>(logits, target, feat, masks, preds, ws);
  sim_kernel<<<256, 256, 0, stream>>>(feat, ws);
  final_kernel<<<1, 1024, 0, stream>>>(ws, out);
}

// Round 3
// 52.054 us; speedup vs baseline: 5.1097x; 1.6762x over previous
//
#include <hip/hip_runtime.h>
#include <math.h>

// ws layout (float offsets) — every slot written fresh each call, no atomics
#define WS_FOCALP 0        // 2048 focal block partials
#define WS_CONSP  2048     // 6*2048 consensus partials, [k][b]
#define WS_AREAP  14336    // 512 (img*16+part)
#define WS_EXP_   14848    // 512
#define WS_EYP_   15360    // 512
#define WS_POS    15872    // 1024
#define WS_PART   16896    // 1024*32 float2 (m,s)  -> 65536 floats
// bf16 planes (byte offsets into ws): row-major [1024][512] bf16 = 1 MB each
#define WS_HI_B   393216
#define WS_LO_B   1441792

typedef __attribute__((ext_vector_type(8))) short bf16x8;
typedef __attribute__((ext_vector_type(4))) float f32x4;

__device__ inline float wave_reduce(float v) {
#pragma unroll
  for (int m = 32; m >= 1; m >>= 1) v += __shfl_xor(v, m);
  return v;
}

__device__ inline unsigned short bf16_rne(float x) {
  union { float f; unsigned u; } v; v.f = x;
  unsigned r = v.u + 0x7FFF + ((v.u >> 16) & 1);
  return (unsigned short)(r >> 16);
}
__device__ inline float bf16_f(unsigned short h) {
  union { unsigned u; float f; } v; v.u = ((unsigned)h) << 16; return v.f;
}

__device__ inline float focal_px(float v0, float v1, float v2, float v3,
                                 float v4, float v5, float v6, float v7, int tt) {
  float mx = fmaxf(fmaxf(fmaxf(v0, v1), fmaxf(v2, v3)),
                   fmaxf(fmaxf(v4, v5), fmaxf(v6, v7)));
  float se = expf(v0 - mx) + expf(v1 - mx) + expf(v2 - mx) + expf(v3 - mx) +
             expf(v4 - mx) + expf(v5 - mx) + expf(v6 - mx) + expf(v7 - mx);
  float xt = v0;
  xt = (tt == 1) ? v1 : xt;
  xt = (tt == 2) ? v2 : xt;
  xt = (tt == 3) ? v3 : xt;
  xt = (tt == 4) ? v4 : xt;
  xt = (tt == 5) ? v5 : xt;
  xt = (tt == 6) ? v6 : xt;
  xt = (tt == 7) ? v7 : xt;
  float lp = (xt - mx) - logf(se);
  float p = expf(lp);
  float om = 1.0f - p;
  return 0.25f * om * om * (-lp);
}

// blocks [0,2048): focal | [2048,2560): circularity | [2560,4608): consensus
// [4608,4864): feature norms + normalized bf16 hi/lo split emit
__global__ __launch_bounds__(256) void mega_kernel(
    const float* __restrict__ logits, const int* __restrict__ target,
    const float* __restrict__ feat, const float* __restrict__ masks,
    const float* __restrict__ preds, float* __restrict__ ws) {
  __shared__ float red[32];
  const int bid = blockIdx.x;
  const int tid = threadIdx.x;
  const int lane = tid & 63;
  const int wid = tid >> 6;

  if (bid < 2048) {
    // ---------------- focal ----------------
    int t = bid * 256 + tid;
    int p4 = t * 4;
    int b = p4 >> 16;
    int hw = p4 & 65535;
    const float* lb = logits + (b << 19) + hw;
    float4 x0 = *(const float4*)(lb + (0 << 16));
    float4 x1 = *(const float4*)(lb + (1 << 16));
    float4 x2 = *(const float4*)(lb + (2 << 16));
    float4 x3 = *(const float4*)(lb + (3 << 16));
    float4 x4 = *(const float4*)(lb + (4 << 16));
    float4 x5 = *(const float4*)(lb + (5 << 16));
    float4 x6 = *(const float4*)(lb + (6 << 16));
    float4 x7 = *(const float4*)(lb + (7 << 16));
    int4 tg = *(const int4*)(target + p4);
    float acc = 0.0f;
    acc += focal_px(x0.x, x1.x, x2.x, x3.x, x4.x, x5.x, x6.x, x7.x, tg.x);
    acc += focal_px(x0.y, x1.y, x2.y, x3.y, x4.y, x5.y, x6.y, x7.y, tg.y);
    acc += focal_px(x0.z, x1.z, x2.z, x3.z, x4.z, x5.z, x6.z, x7.z, tg.z);
    acc += focal_px(x0.w, x1.w, x2.w, x3.w, x4.w, x5.w, x6.w, x7.w, tg.w);
    float v = wave_reduce(acc);
    if (lane == 0) red[wid] = v;
    __syncthreads();
    if (tid == 0) ws[WS_FOCALP + bid] = red[0] + red[1] + red[2] + red[3];

  } else if (bid < 2560) {
    // ---------------- circularity ----------------
    int bi = bid - 2048;
    int img = bi >> 4;
    int part = bi & 15;
    const float* mS = masks + img * 3 * 65536;
    const float4* m4 = (const float4*)mS;
    float a = 0.0f, ex = 0.0f, ey = 0.0f;
#pragma unroll
    for (int i = 0; i < 4; i++) {
      int v = tid + 256 * i;
      int rl = v >> 6;
      int c4 = v & 63;
      int row = part * 16 + rl;
      float4 val = m4[row * 64 + c4];
      a += val.x + val.y + val.z + val.w;
      ey += fabsf(val.y - val.x) + fabsf(val.z - val.y) + fabsf(val.w - val.z);
      if (c4 > 0) ey += fabsf(val.x - mS[row * 256 + c4 * 4 - 1]);
      if (row > 0) {
        float4 u = m4[(row - 1) * 64 + c4];
        ex += fabsf(val.x - u.x) + fabsf(val.y - u.y) +
              fabsf(val.z - u.z) + fabsf(val.w - u.w);
      }
    }
    float ra = wave_reduce(a);
    float rx = wave_reduce(ex);
    float ry = wave_reduce(ey);
    if (lane == 0) {
      red[wid + 0] = ra; red[wid + 4] = rx; red[wid + 8] = ry;
    }
    __syncthreads();
    if (tid == 0) {
      ws[WS_AREAP + bi] = red[0] + red[1] + red[2] + red[3];
      ws[WS_EXP_ + bi] = red[4] + red[5] + red[6] + red[7];
      ws[WS_EYP_ + bi] = red[8] + red[9] + red[10] + red[11];
    }

  } else if (bid < 4608) {
    // ---------------- consensus ----------------
    int b = bid - 2560;
    int t = b * 256 + tid;
    const float4* q = (const float4*)preds;
    float4 a0 = q[t];
    float4 a1 = q[t + 524288];
    float4 a2 = q[t + 1048576];
    float s0 = a0.x + a0.y + a0.z + a0.w;
    float s1 = a1.x + a1.y + a1.z + a1.w;
    float s2 = a2.x + a2.y + a2.z + a2.w;
    float p01 = a0.x * a1.x + a0.y * a1.y + a0.z * a1.z + a0.w * a1.w;
    float p02 = a0.x * a2.x + a0.y * a2.y + a0.z * a2.z + a0.w * a2.w;
    float p12 = a1.x * a2.x + a1.y * a2.y + a1.z * a2.z + a1.w * a2.w;
    float r0 = wave_reduce(s0);
    float r1 = wave_reduce(s1);
    float r2 = wave_reduce(s2);
    float r3 = wave_reduce(p01);
    float r4 = wave_reduce(p02);
    float r5 = wave_reduce(p12);
    if (lane == 0) {
      red[wid + 0] = r0; red[wid + 4] = r1; red[wid + 8] = r2;
      red[wid + 12] = r3; red[wid + 16] = r4; red[wid + 20] = r5;
    }
    __syncthreads();
    if (tid == 0) {
#pragma unroll
      for (int k = 0; k < 6; k++)
        ws[WS_CONSP + k * 2048 + b] =
            red[k * 4] + red[k * 4 + 1] + red[k * 4 + 2] + red[k * 4 + 3];
    }

  } else {
    // ------- feature norms + normalized bf16 split (hi/lo planes) -------
    int row = (bid - 4608) * 4 + wid;  // 0..1023
    const float4* f4 = (const float4*)feat;
    float4 u = f4[row * 128 + lane];
    float4 w = f4[row * 128 + 64 + lane];
    float s = u.x * u.x + u.y * u.y + u.z * u.z + u.w * u.w +
              w.x * w.x + w.y * w.y + w.z * w.z + w.w * w.w;
    s = wave_reduce(s);
    // scale = (1/|f|) * sqrt(1/0.07) so that g.g^T == sim/T directly
    float scale = 3.7796447300922719f / sqrtf(s);
    float g[8] = {u.x * scale, u.y * scale, u.z * scale, u.w * scale,
                  w.x * scale, w.y * scale, w.z * scale, w.w * scale};
    unsigned short h[8];
    unsigned short l[8];
#pragma unroll
    for (int i = 0; i < 8; i++) {
      h[i] = bf16_rne(g[i]);
      l[i] = bf16_rne(g[i] - bf16_f(h[i]));
    }
    char* hb = (char*)ws + WS_HI_B + row * 1024;
    char* lb = (char*)ws + WS_LO_B + row * 1024;
    *(ushort4*)(hb + lane * 8) = make_ushort4(h[0], h[1], h[2], h[3]);
    *(ushort4*)(hb + 512 + lane * 8) = make_ushort4(h[4], h[5], h[6], h[7]);
    *(ushort4*)(lb + lane * 8) = make_ushort4(l[0], l[1], l[2], l[3]);
    *(ushort4*)(lb + 512 + lane * 8) = make_ushort4(l[4], l[5], l[6], l[7]);
  }
}

// MFMA sim: C = G.G^T with G = Hi + Lo (bf16 split of normalized/scaled feat).
// Virtual K = 1536: segs {A=Hi,B=Hi}, {A=Hi,B=Lo}, {A=Lo,B=Hi}.
// 512 blocks: rt=bid>>4 (32 row-tiles of 32), ct=bid&15 (16 col-tiles of 64).
// 4 waves: wr=wid>>1 rows, wc=wid&1 cols; per-wave 16x32 via 2 mfma tiles.
// Fused per-row (m,s) LSE partials over 32-col groups -> WS_PART[1024][32].
__global__ __launch_bounds__(256) void sim_kernel(float* __restrict__ ws) {
  __shared__ __align__(16) char lds[49152];  // 2 bufs x (A 8KB | B 16KB)
  const int tid = threadIdx.x;
  const int lane = tid & 63;
  const int wid = tid >> 6;
  const int wr = wid >> 1, wc = wid & 1;
  const int rt = blockIdx.x >> 4, ct = blockIdx.x & 15;
  const int rb = rt * 32, cb = ct * 64;
  const int hi8 = lane >> 4;       // 0..3
  const int l15 = lane & 15;
  const int lr_a = wr * 16 + l15;  // local A row 0..31
  const int rb0 = wc * 32 + l15;   // local B row (= col) 0..63
  const int rb1 = rb0 + 16;

  f32x4 acc0 = {0.f, 0.f, 0.f, 0.f};
  f32x4 acc1 = {0.f, 0.f, 0.f, 0.f};

  auto stage = [&](int ch) {
    const char* srcA = (const char*)ws + (ch < 8 ? WS_HI_B : WS_LO_B);
    const char* srcB = (const char*)ws + ((ch >> 2) == 1 ? WS_LO_B : WS_HI_B);
    int koff = (ch & 3) * 256;  // byte offset within 512-k segment
    char* dst = lds + (ch & 1) * 24576;
#pragma unroll
    for (int rr = 0; rr < 6; rr++) {
      int idx = rr * 256 + tid;
      const char* g;
      if (rr < 2) {  // A region: 32 rows x 256B
        int row = idx >> 4, sl = idx & 15;
        g = srcA + (rb + row) * 1024 + koff + ((sl ^ (row & 7)) << 4);
      } else {  // B region: 64 rows x 256B
        int i2 = idx - 512;
        int row = i2 >> 4, sl = i2 & 15;
        g = srcB + (cb + row) * 1024 + koff + ((sl ^ (row & 7)) << 4);
      }
      __builtin_amdgcn_global_load_lds(
          (const __attribute__((address_space(1))) unsigned int*)g,
          (__attribute__((address_space(3))) unsigned int*)(dst + idx * 16),
          16, 0, 0);
    }
  };

  auto compute = [&](int buf) {
    const char* bp = lds + buf * 24576;
#pragma unroll
    for (int j = 0; j < 4; j++) {
      int sa = (j * 4 + hi8) ^ (lr_a & 7);
      bf16x8 a = *(const bf16x8*)(bp + lr_a * 256 + sa * 16);
      int sb0 = (j * 4 + hi8) ^ (rb0 & 7);
      bf16x8 b0 = *(const bf16x8*)(bp + 8192 + rb0 * 256 + sb0 * 16);
      int sb1 = (j * 4 + hi8) ^ (rb1 & 7);
      bf16x8 b1 = *(const bf16x8*)(bp + 8192 + rb1 * 256 + sb1 * 16);
      acc0 = __builtin_amdgcn_mfma_f32_16x16x32_bf16(a, b0, acc0, 0, 0, 0);
      acc1 = __builtin_amdgcn_mfma_f32_16x16x32_bf16(a, b1, acc1, 0, 0, 0);
    }
  };

  stage(0);
  __syncthreads();
#pragma unroll 1
  for (int ch = 0; ch < 12; ch++) {
    if (ch + 1 < 12) stage(ch + 1);
    compute(ch & 1);
    __syncthreads();
  }

  // epilogue: D row=(lane>>4)*4+q, col=lane&15 (per tile)
  int c0 = cb + wc * 32 + l15;
  int c1 = c0 + 16;
  float2* part = (float2*)(ws + WS_PART);
#pragma unroll
  for (int q = 0; q < 4; q++) {
    int r = rb + wr * 16 + hi8 * 4 + q;
    float v0 = acc0[q], v1 = acc1[q];
    int pc = (r + 512) & 1023;
    if (c0 == pc) ws[WS_POS + r] = v0;
    if (c1 == pc) ws[WS_POS + r] = v1;
    if (c0 == r) v0 = -1e30f;
    if (c1 == r) v1 = -1e30f;
    float m = fmaxf(v0, v1);
    float s = expf(v0 - m) + expf(v1 - m);
#pragma unroll
    for (int d = 1; d < 16; d <<= 1) {
      float mo = __shfl_xor(m, d), so = __shfl_xor(s, d);
      float nm = fmaxf(m, mo);
      s = s * expf(m - nm) + so * expf(mo - nm);
      m = nm;
    }
    if (l15 == 0) part[r * 32 + ct * 2 + wc] = make_float2(m, s);
  }
}

// returns block total at tid==0 (valid only there)
__device__ inline float block_reduce_1024(float v, float* red) {
  int tid = threadIdx.x;
  v = wave_reduce(v);
  __syncthreads();
  if ((tid & 63) == 0) red[tid >> 6] = v;
  __syncthreads();
  float t = 0.0f;
  if (tid == 0) {
#pragma unroll
    for (int i = 0; i < 16; i++) t += red[i];
  }
  return t;
}

__global__ __launch_bounds__(1024) void final_kernel(float* __restrict__ ws,
                                                     float* __restrict__ out) {
  __shared__ float red[16];
  __shared__ float li_s[32];
  int r = threadIdx.x;  // 0..1023

  // ---- contrastive LSE merge over 32 col-tiles ----
  const float2* part = (const float2*)(ws + WS_PART);
  float M = -1e30f, S = 0.0f;
#pragma unroll
  for (int ctl = 0; ctl < 32; ctl++) {
    float2 p = part[r * 32 + ctl];
    float nm = fmaxf(M, p.x);
    S = S * expf(M - nm) + p.y * expf(p.x - nm);
    M = nm;
  }
  float lse = M + logf(S);
  float contr_sum = block_reduce_1024(lse - ws[WS_POS + r], red);

  // ---- focal partials ----
  float focal_sum =
      block_reduce_1024(ws[WS_FOCALP + r] + ws[WS_FOCALP + r + 1024], red);

  // ---- consensus partials ----
  float cons[6];
#pragma unroll
  for (int k = 0; k < 6; k++) {
    const float* p = ws + WS_CONSP + k * 2048;
    cons[k] = block_reduce_1024(p[r] + p[r + 1024], red);
  }

  // ---- circularity ----
  float li = 0.0f;
  if (r < 512) {
    float a = ws[WS_AREAP + r];
    float ex = ws[WS_EXP_ + r];
    float ey = ws[WS_EYP_ + r];
#pragma unroll
    for (int d = 1; d < 16; d <<= 1) {
      a += __shfl_xor(a, d);
      ex += __shfl_xor(ex, d);
      ey += __shfl_xor(ey, d);
    }
    if ((r & 15) == 0) {
      float per = ex + ey;
      float dd = fmaxf(per, 1e-12f);
      float c = 12.566370614359172f * a / (dd * dd);
      li = (a > 0.0f && per > 0.0f) ? (c - 1.0f) * (c - 1.0f) : 0.0f;
      li_s[r >> 4] = li;
    }
  }
  __syncthreads();

  if (r == 0) {
    float circ = 0.0f;
#pragma unroll
    for (int i = 0; i < 32; i++) circ += li_s[i];
    circ = 0.1f * circ / 32.0f;

    float contr = contr_sum / 1024.0f;
    float focal = focal_sum / 2097152.0f;

    float S0 = cons[0], S1 = cons[1], S2 = cons[2];
    float P01 = cons[3], P02 = cons[4], P12 = cons[5];
    float co = 0.0f;
    co += fmaxf(0.6f - P01 / (S0 + S1 - P01 + 1e-6f), 0.0f);
    co += fmaxf(0.6f - P02 / (S0 + S2 - P02 + 1e-6f), 0.0f);
    co += fmaxf(0.6f - P12 / (S1 + S2 - P12 + 1e-6f), 0.0f);
    co *= (1.0f / 3.0f);

    out[0] = focal + 0.5f * contr + circ + 0.3f * co;
  }
}

extern "C" void kernel_launch(void* const* d_in, const int* in_sizes, int n_in,
                              void* d_out, int out_size, void* d_ws, size_t ws_size,
                              hipStream_t stream) {
  const float* logits = (const float*)d_in[0];
  const int* target = (const int*)d_in[1];
  const float* feat = (const float*)d_in[2];
  const float* masks = (const float*)d_in[3];
  const float* preds = (const float*)d_in[4];
  float* ws = (float*)d_ws;
  float* out = (float*)d_out;

  mega_kernel<<<4864, 256, 0, stream>>>(logits, target, feat, masks, preds, ws);
  sim_kernel<<<512, 256, 0, stream>>>(ws);
  final_kernel<<<1, 1024, 0, stream>>>(ws, out);
}

// Round 4
// 50.178 us; speedup vs baseline: 5.3007x; 1.0374x over previous
//
#include <hip/hip_runtime.h>
#include <math.h>

// ws layout (float offsets) — every slot written fresh each call, no atomics
#define WS_FOCALP 0        // 2048 focal block partials
#define WS_CONSP  2048     // 6*2048 consensus partials, [k][b]
#define WS_AREAP  14336    // 512 (img*16+part)
#define WS_EXP_   14848    // 512
#define WS_EYP_   15360    // 512
#define WS_POS    15872    // 1024
#define WS_PART   16896    // 1024*32 float2 (m,s)  -> 65536 floats
// bf16 planes (byte offsets into ws): row-major [1024][512] bf16 = 1 MB each
#define WS_HI_B   393216
#define WS_LO_B   1441792

typedef __attribute__((ext_vector_type(8))) short bf16x8;
typedef __attribute__((ext_vector_type(4))) float f32x4;

__device__ inline float wave_reduce(float v) {
#pragma unroll
  for (int m = 32; m >= 1; m >>= 1) v += __shfl_xor(v, m);
  return v;
}

__device__ inline unsigned short bf16_rne(float x) {
  union { float f; unsigned u; } v; v.f = x;
  unsigned r = v.u + 0x7FFF + ((v.u >> 16) & 1);
  return (unsigned short)(r >> 16);
}
__device__ inline float bf16_f(unsigned short h) {
  union { unsigned u; float f; } v; v.u = ((unsigned)h) << 16; return v.f;
}

__device__ inline float focal_px(float v0, float v1, float v2, float v3,
                                 float v4, float v5, float v6, float v7, int tt) {
  float mx = fmaxf(fmaxf(fmaxf(v0, v1), fmaxf(v2, v3)),
                   fmaxf(fmaxf(v4, v5), fmaxf(v6, v7)));
  float se = __expf(v0 - mx) + __expf(v1 - mx) + __expf(v2 - mx) + __expf(v3 - mx) +
             __expf(v4 - mx) + __expf(v5 - mx) + __expf(v6 - mx) + __expf(v7 - mx);
  float xt = v0;
  xt = (tt == 1) ? v1 : xt;
  xt = (tt == 2) ? v2 : xt;
  xt = (tt == 3) ? v3 : xt;
  xt = (tt == 4) ? v4 : xt;
  xt = (tt == 5) ? v5 : xt;
  xt = (tt == 6) ? v6 : xt;
  xt = (tt == 7) ? v7 : xt;
  float lp = (xt - mx) - __logf(se);
  float p = __expf(lp);
  float om = 1.0f - p;
  return 0.25f * om * om * (-lp);
}

// ---------- prep: feature norms + normalized bf16 hi/lo split emit ----------
__global__ __launch_bounds__(256) void prep_kernel(const float* __restrict__ feat,
                                                   float* __restrict__ ws) {
  const int tid = threadIdx.x;
  const int lane = tid & 63;
  const int wid = tid >> 6;
  int row = blockIdx.x * 4 + wid;  // 0..1023
  const float4* f4 = (const float4*)feat;
  float4 u = f4[row * 128 + lane];
  float4 w = f4[row * 128 + 64 + lane];
  float s = u.x * u.x + u.y * u.y + u.z * u.z + u.w * u.w +
            w.x * w.x + w.y * w.y + w.z * w.z + w.w * w.w;
  s = wave_reduce(s);
  // scale = (1/|f|) * sqrt(1/0.07) so that g.g^T == sim/T directly
  float scale = 3.7796447300922719f / sqrtf(s);
  float g[8] = {u.x * scale, u.y * scale, u.z * scale, u.w * scale,
                w.x * scale, w.y * scale, w.z * scale, w.w * scale};
  unsigned short h[8];
  unsigned short l[8];
#pragma unroll
  for (int i = 0; i < 8; i++) {
    h[i] = bf16_rne(g[i]);
    l[i] = bf16_rne(g[i] - bf16_f(h[i]));
  }
  char* hb = (char*)ws + WS_HI_B + row * 1024;
  char* lb = (char*)ws + WS_LO_B + row * 1024;
  *(ushort4*)(hb + lane * 8) = make_ushort4(h[0], h[1], h[2], h[3]);
  *(ushort4*)(hb + 512 + lane * 8) = make_ushort4(h[4], h[5], h[6], h[7]);
  *(ushort4*)(lb + lane * 8) = make_ushort4(l[0], l[1], l[2], l[3]);
  *(ushort4*)(lb + 512 + lane * 8) = make_ushort4(l[4], l[5], l[6], l[7]);
}

// ---------- fused: blocks [0,512) = MFMA sim; [512,5120) = focal/circ/cons ---
// sim: C = G.G^T, G = Hi + Lo. Virtual K = 1536: {Hi,Hi},{Hi,Lo},{Lo,Hi}.
// sim block: rt=bid>>4 (32 row-tiles of 32), ct=bid&15 (16 col-tiles of 64).
// 4 waves: per-wave 16x32 via 2 mfma tiles; fused per-row (m,s) LSE partials.
__global__ __launch_bounds__(256) void fused_kernel(
    const float* __restrict__ logits, const int* __restrict__ target,
    const float* __restrict__ masks, const float* __restrict__ preds,
    float* __restrict__ ws) {
  __shared__ __align__(16) char lds[49152];  // sim: 2 bufs x (A 8KB | B 16KB)
  const int bid = blockIdx.x;
  const int tid = threadIdx.x;
  const int lane = tid & 63;
  const int wid = tid >> 6;

  if (bid < 512) {
    // ================= sim (MFMA) =================
    const int wr = wid >> 1, wc = wid & 1;
    const int rt = bid >> 4, ct = bid & 15;
    const int rb = rt * 32, cb = ct * 64;
    const int hi8 = lane >> 4;       // 0..3
    const int l15 = lane & 15;
    const int lr_a = wr * 16 + l15;  // local A row 0..31
    const int rb0 = wc * 32 + l15;   // local B row (= col) 0..63
    const int rb1 = rb0 + 16;

    f32x4 acc0 = {0.f, 0.f, 0.f, 0.f};
    f32x4 acc1 = {0.f, 0.f, 0.f, 0.f};

    auto stage = [&](int ch) {
      const char* srcA = (const char*)ws + (ch < 8 ? WS_HI_B : WS_LO_B);
      const char* srcB = (const char*)ws + ((ch >> 2) == 1 ? WS_LO_B : WS_HI_B);
      int koff = (ch & 3) * 256;  // byte offset within 512-k segment
      char* dst = lds + (ch & 1) * 24576;
#pragma unroll
      for (int rr = 0; rr < 6; rr++) {
        int idx = rr * 256 + tid;
        const char* g;
        if (rr < 2) {  // A region: 32 rows x 256B
          int row = idx >> 4, sl = idx & 15;
          g = srcA + (rb + row) * 1024 + koff + ((sl ^ (row & 7)) << 4);
        } else {  // B region: 64 rows x 256B
          int i2 = idx - 512;
          int row = i2 >> 4, sl = i2 & 15;
          g = srcB + (cb + row) * 1024 + koff + ((sl ^ (row & 7)) << 4);
        }
        __builtin_amdgcn_global_load_lds(
            (const __attribute__((address_space(1))) unsigned int*)g,
            (__attribute__((address_space(3))) unsigned int*)(dst + idx * 16),
            16, 0, 0);
      }
    };

    auto compute = [&](int buf) {
      const char* bp = lds + buf * 24576;
#pragma unroll
      for (int j = 0; j < 4; j++) {
        int sa = (j * 4 + hi8) ^ (lr_a & 7);
        bf16x8 a = *(const bf16x8*)(bp + lr_a * 256 + sa * 16);
        int sb0 = (j * 4 + hi8) ^ (rb0 & 7);
        bf16x8 b0 = *(const bf16x8*)(bp + 8192 + rb0 * 256 + sb0 * 16);
        int sb1 = (j * 4 + hi8) ^ (rb1 & 7);
        bf16x8 b1 = *(const bf16x8*)(bp + 8192 + rb1 * 256 + sb1 * 16);
        acc0 = __builtin_amdgcn_mfma_f32_16x16x32_bf16(a, b0, acc0, 0, 0, 0);
        acc1 = __builtin_amdgcn_mfma_f32_16x16x32_bf16(a, b1, acc1, 0, 0, 0);
      }
    };

    stage(0);
    __syncthreads();
#pragma unroll 1
    for (int ch = 0; ch < 12; ch++) {
      if (ch + 1 < 12) stage(ch + 1);
      compute(ch & 1);
      __syncthreads();
    }

    // epilogue: D row=(lane>>4)*4+q, col=lane&15 (per tile)
    int c0 = cb + wc * 32 + l15;
    int c1 = c0 + 16;
    float2* part = (float2*)(ws + WS_PART);
#pragma unroll
    for (int q = 0; q < 4; q++) {
      int r = rb + wr * 16 + hi8 * 4 + q;
      float v0 = acc0[q], v1 = acc1[q];
      int pc = (r + 512) & 1023;
      if (c0 == pc) ws[WS_POS + r] = v0;
      if (c1 == pc) ws[WS_POS + r] = v1;
      if (c0 == r) v0 = -1e30f;
      if (c1 == r) v1 = -1e30f;
      float m = fmaxf(v0, v1);
      float s = __expf(v0 - m) + __expf(v1 - m);
#pragma unroll
      for (int d = 1; d < 16; d <<= 1) {
        float mo = __shfl_xor(m, d), so = __shfl_xor(s, d);
        float nm = fmaxf(m, mo);
        s = s * __expf(m - nm) + so * __expf(mo - nm);
        m = nm;
      }
      if (l15 == 0) part[r * 32 + ct * 2 + wc] = make_float2(m, s);
    }
    return;
  }

  float* red = (float*)lds;  // reuse sim's LDS for reductions
  const int bid2 = bid - 512;

  if (bid2 < 2048) {
    // ================= focal =================
    int t = bid2 * 256 + tid;
    int p4 = t * 4;
    int b = p4 >> 16;
    int hw = p4 & 65535;
    const float* lb = logits + (b << 19) + hw;
    float4 x0 = *(const float4*)(lb + (0 << 16));
    float4 x1 = *(const float4*)(lb + (1 << 16));
    float4 x2 = *(const float4*)(lb + (2 << 16));
    float4 x3 = *(const float4*)(lb + (3 << 16));
    float4 x4 = *(const float4*)(lb + (4 << 16));
    float4 x5 = *(const float4*)(lb + (5 << 16));
    float4 x6 = *(const float4*)(lb + (6 << 16));
    float4 x7 = *(const float4*)(lb + (7 << 16));
    int4 tg = *(const int4*)(target + p4);
    float acc = 0.0f;
    acc += focal_px(x0.x, x1.x, x2.x, x3.x, x4.x, x5.x, x6.x, x7.x, tg.x);
    acc += focal_px(x0.y, x1.y, x2.y, x3.y, x4.y, x5.y, x6.y, x7.y, tg.y);
    acc += focal_px(x0.z, x1.z, x2.z, x3.z, x4.z, x5.z, x6.z, x7.z, tg.z);
    acc += focal_px(x0.w, x1.w, x2.w, x3.w, x4.w, x5.w, x6.w, x7.w, tg.w);
    float v = wave_reduce(acc);
    if (lane == 0) red[wid] = v;
    __syncthreads();
    if (tid == 0) ws[WS_FOCALP + bid2] = red[0] + red[1] + red[2] + red[3];

  } else if (bid2 < 2560) {
    // ================= circularity =================
    int bi = bid2 - 2048;
    int img = bi >> 4;
    int part = bi & 15;
    const float* mS = masks + img * 3 * 65536;
    const float4* m4 = (const float4*)mS;
    float a = 0.0f, ex = 0.0f, ey = 0.0f;
#pragma unroll
    for (int i = 0; i < 4; i++) {
      int v = tid + 256 * i;
      int rl = v >> 6;
      int c4 = v & 63;
      int row = part * 16 + rl;
      float4 val = m4[row * 64 + c4];
      a += val.x + val.y + val.z + val.w;
      ey += fabsf(val.y - val.x) + fabsf(val.z - val.y) + fabsf(val.w - val.z);
      if (c4 > 0) ey += fabsf(val.x - mS[row * 256 + c4 * 4 - 1]);
      if (row > 0) {
        float4 u = m4[(row - 1) * 64 + c4];
        ex += fabsf(val.x - u.x) + fabsf(val.y - u.y) +
              fabsf(val.z - u.z) + fabsf(val.w - u.w);
      }
    }
    float ra = wave_reduce(a);
    float rx = wave_reduce(ex);
    float ry = wave_reduce(ey);
    if (lane == 0) {
      red[wid + 0] = ra; red[wid + 4] = rx; red[wid + 8] = ry;
    }
    __syncthreads();
    if (tid == 0) {
      ws[WS_AREAP + bi] = red[0] + red[1] + red[2] + red[3];
      ws[WS_EXP_ + bi] = red[4] + red[5] + red[6] + red[7];
      ws[WS_EYP_ + bi] = red[8] + red[9] + red[10] + red[11];
    }

  } else {
    // ================= consensus =================
    int b = bid2 - 2560;
    int t = b * 256 + tid;
    const float4* q = (const float4*)preds;
    float4 a0 = q[t];
    float4 a1 = q[t + 524288];
    float4 a2 = q[t + 1048576];
    float s0 = a0.x + a0.y + a0.z + a0.w;
    float s1 = a1.x + a1.y + a1.z + a1.w;
    float s2 = a2.x + a2.y + a2.z + a2.w;
    float p01 = a0.x * a1.x + a0.y * a1.y + a0.z * a1.z + a0.w * a1.w;
    float p02 = a0.x * a2.x + a0.y * a2.y + a0.z * a2.z + a0.w * a2.w;
    float p12 = a1.x * a2.x + a1.y * a2.y + a1.z * a2.z + a1.w * a2.w;
    float r0 = wave_reduce(s0);
    float r1 = wave_reduce(s1);
    float r2 = wave_reduce(s2);
    float r3 = wave_reduce(p01);
    float r4 = wave_reduce(p02);
    float r5 = wave_reduce(p12);
    if (lane == 0) {
      red[wid + 0] = r0; red[wid + 4] = r1; red[wid + 8] = r2;
      red[wid + 12] = r3; red[wid + 16] = r4; red[wid + 20] = r5;
    }
    __syncthreads();
    if (tid == 0) {
#pragma unroll
      for (int k = 0; k < 6; k++)
        ws[WS_CONSP + k * 2048 + b] =
            red[k * 4] + red[k * 4 + 1] + red[k * 4 + 2] + red[k * 4 + 3];
    }
  }
}

// returns block total at tid==0 (valid only there)
__device__ inline float block_reduce_1024(float v, float* red) {
  int tid = threadIdx.x;
  v = wave_reduce(v);
  __syncthreads();
  if ((tid & 63) == 0) red[tid >> 6] = v;
  __syncthreads();
  float t = 0.0f;
  if (tid == 0) {
#pragma unroll
    for (int i = 0; i < 16; i++) t += red[i];
  }
  return t;
}

__global__ __launch_bounds__(1024) void final_kernel(float* __restrict__ ws,
                                                     float* __restrict__ out) {
  __shared__ float red[16];
  __shared__ float li_s[32];
  int r = threadIdx.x;  // 0..1023

  // ---- contrastive LSE merge over 32 col-tiles ----
  const float2* part = (const float2*)(ws + WS_PART);
  float M = -1e30f, S = 0.0f;
#pragma unroll
  for (int ctl = 0; ctl < 32; ctl++) {
    float2 p = part[r * 32 + ctl];
    float nm = fmaxf(M, p.x);
    S = S * __expf(M - nm) + p.y * __expf(p.x - nm);
    M = nm;
  }
  float lse = M + __logf(S);
  float contr_sum = block_reduce_1024(lse - ws[WS_POS + r], red);

  // ---- focal partials ----
  float focal_sum =
      block_reduce_1024(ws[WS_FOCALP + r] + ws[WS_FOCALP + r + 1024], red);

  // ---- consensus partials ----
  float cons[6];
#pragma unroll
  for (int k = 0; k < 6; k++) {
    const float* p = ws + WS_CONSP + k * 2048;
    cons[k] = block_reduce_1024(p[r] + p[r + 1024], red);
  }

  // ---- circularity ----
  float li = 0.0f;
  if (r < 512) {
    float a = ws[WS_AREAP + r];
    float ex = ws[WS_EXP_ + r];
    float ey = ws[WS_EYP_ + r];
#pragma unroll
    for (int d = 1; d < 16; d <<= 1) {
      a += __shfl_xor(a, d);
      ex += __shfl_xor(ex, d);
      ey += __shfl_xor(ey, d);
    }
    if ((r & 15) == 0) {
      float per = ex + ey;
      float dd = fmaxf(per, 1e-12f);
      float c = 12.566370614359172f * a / (dd * dd);
      li = (a > 0.0f && per > 0.0f) ? (c - 1.0f) * (c - 1.0f) : 0.0f;
      li_s[r >> 4] = li;
    }
  }
  __syncthreads();

  if (r == 0) {
    float circ = 0.0f;
#pragma unroll
    for (int i = 0; i < 32; i++) circ += li_s[i];
    circ = 0.1f * circ / 32.0f;

    float contr = contr_sum / 1024.0f;
    float focal = focal_sum / 2097152.0f;

    float S0 = cons[0], S1 = cons[1], S2 = cons[2];
    float P01 = cons[3], P02 = cons[4], P12 = cons[5];
    float co = 0.0f;
    co += fmaxf(0.6f - P01 / (S0 + S1 - P01 + 1e-6f), 0.0f);
    co += fmaxf(0.6f - P02 / (S0 + S2 - P02 + 1e-6f), 0.0f);
    co += fmaxf(0.6f - P12 / (S1 + S2 - P12 + 1e-6f), 0.0f);
    co *= (1.0f / 3.0f);

    out[0] = focal + 0.5f * contr + circ + 0.3f * co;
  }
}

extern "C" void kernel_launch(void* const* d_in, const int* in_sizes, int n_in,
                              void* d_out, int out_size, void* d_ws, size_t ws_size,
                              hipStream_t stream) {
  const float* logits = (const float*)d_in[0];
  const int* target = (const int*)d_in[1];
  const float* feat = (const float*)d_in[2];
  const float* masks = (const float*)d_in[3];
  const float* preds = (const float*)d_in[4];
  float* ws = (float*)d_ws;
  float* out = (float*)d_out;

  prep_kernel<<<256, 256, 0, stream>>>(feat, ws);
  fused_kernel<<<5120, 256, 0, stream>>>(logits, target, masks, preds, ws);
  final_kernel<<<1, 1024, 0, stream>>>(ws, out);
}